// Round 4
// baseline (228.604 us; speedup 1.0000x reference)
//
#include <hip/hip_runtime.h>

#define BATCH 8
#define CCH 8
#define HW 262144       // 512*512
#define SEGS 16         // segments 1..16 (segment 0 is provably ignored by the reference)
#define GX 128          // blocks per batch
#define GQ 8            // lane-iterations per block: GX * 64 * GQ == HW/4 exactly

// ws float layout:
//   [0, 128)      counts[b][s]
//   [128, 1152)   sums[b][s][c]
//   [1152, 1280)  pen_sum[b][s]

// ---------------------------------------------------------------------------
// Pass 1: counts + per-channel sums.
// One-hot REGISTER accumulation, channel-split: wave w owns channels {2w,2w+1}
// over the block's whole pixel range (all 4 waves iterate the same g, lab/msk
// hits L1 after wave 0). NO LDS ops at all. One butterfly + one commit per
// wave at the end (atomic work amortized over 512 pixels/wave).
// __launch_bounds__(256,2): 256-VGPR budget so the ~100-reg working set does
// NOT spill (round-2 failure) and loads stay hoisted (round-3 failure).
// ---------------------------------------------------------------------------
__global__ __launch_bounds__(256, 2) void accum_kernel(
    const float* __restrict__ emb, const int* __restrict__ lab,
    const int* __restrict__ msk, float* __restrict__ ws)
{
    const int b = blockIdx.y;
    const int wave = threadIdx.x >> 6;
    const int lane = threadIdx.x & 63;
    const int c0 = wave * 2;

    float s0[SEGS], s1[SEGS], cnt[SEGS];
#pragma unroll
    for (int s = 0; s < SEGS; ++s) { s0[s] = 0.f; s1[s] = 0.f; cnt[s] = 0.f; }

    const int4* lb = (const int4*)(lab + (size_t)b * HW);
    const int4* mb = (const int4*)(msk + (size_t)b * HW);
    const float4* ep0 = (const float4*)(emb + (size_t)b * CCH * HW + (size_t)c0 * HW);
    const float4* ep1 = (const float4*)(emb + (size_t)b * CCH * HW + (size_t)(c0 + 1) * HW);

    const int gbase = blockIdx.x * (64 * GQ);
#pragma unroll 2
    for (int q = 0; q < GQ; ++q) {
        const int g = gbase + q * 64 + lane;
        int4 l4 = lb[g];
        int4 m4 = mb[g];
        float4 ea = ep0[g];
        float4 ec = ep1[g];
        int id[4] = { m4.x ? l4.x : 0, m4.y ? l4.y : 0,
                      m4.z ? l4.z : 0, m4.w ? l4.w : 0 };
        float e0v[4] = { ea.x, ea.y, ea.z, ea.w };
        float e1v[4] = { ec.x, ec.y, ec.z, ec.w };
#pragma unroll
        for (int j = 0; j < 4; ++j) {
#pragma unroll
            for (int s = 0; s < SEGS; ++s) {
                float oh = (id[j] == s + 1) ? 1.0f : 0.0f;   // branch-free: loads always consumed
                cnt[s] += oh;
                s0[s] = fmaf(oh, e0v[j], s0[s]);
                s1[s] = fmaf(oh, e1v[j], s1[s]);
            }
        }
    }

    // 64-lane butterfly reduction of the 48 per-lane accumulators
#pragma unroll
    for (int s = 0; s < SEGS; ++s) {
#pragma unroll
        for (int m = 32; m >= 1; m >>= 1) {
            s0[s]  += __shfl_xor(s0[s], m);
            s1[s]  += __shfl_xor(s1[s], m);
            cnt[s] += __shfl_xor(cnt[s], m);
        }
    }
    // one commit per wave (global-atomic depth per word = GX = 128, proven cheap)
    if (lane == 0) {
#pragma unroll
        for (int s = 0; s < SEGS; ++s) {
            if (s0[s] != 0.f) atomicAdd(&ws[128 + (b * SEGS + s) * CCH + c0],     s0[s]);
            if (s1[s] != 0.f) atomicAdd(&ws[128 + (b * SEGS + s) * CCH + c0 + 1], s1[s]);
        }
        if (wave == 0) {
#pragma unroll
            for (int s = 0; s < SEGS; ++s)
                if (cnt[s] != 0.f) atomicAdd(&ws[b * SEGS + s], cnt[s]);
        }
    }
}

// ---------------------------------------------------------------------------
// Pass 2: hinged pull penalties. pens[16] one-hot register accumulation,
// butterfly, LDS-combine of the 4 wave partials, 16 global atomics per block.
// mt[c][*] reads are same-address broadcasts across lanes -> conflict-free.
// ---------------------------------------------------------------------------
__global__ __launch_bounds__(256, 2) void pull_kernel(
    const float* __restrict__ emb, const int* __restrict__ lab,
    const int* __restrict__ msk, float* __restrict__ ws)
{
    const int b = blockIdx.y;
    const int wave = threadIdx.x >> 6;
    const int lane = threadIdx.x & 63;
    __shared__ float mt[CCH][SEGS];
    __shared__ float lpen[4][SEGS];

    if (threadIdx.x < SEGS * CCH) {
        int s = threadIdx.x & (SEGS - 1);
        int c = threadIdx.x >> 4;
        float cv = ws[b * SEGS + s];
        mt[c][s] = ws[128 + (b * SEGS + s) * CCH + c] / fmaxf(cv, 1.0f);
    }
    __syncthreads();

    float pens[SEGS];
#pragma unroll
    for (int s = 0; s < SEGS; ++s) pens[s] = 0.f;

    const int4* lb = (const int4*)(lab + (size_t)b * HW);
    const int4* mb = (const int4*)(msk + (size_t)b * HW);
    const float4* ep = (const float4*)(emb + (size_t)b * CCH * HW);

    const int ng = HW / 4;
    for (int g = blockIdx.x * 256 + threadIdx.x; g < ng; g += GX * 256) {
        int4 l4 = lb[g];
        int4 m4 = mb[g];
        float4 e[CCH];
#pragma unroll
        for (int c = 0; c < CCH; ++c) e[c] = ep[(size_t)c * (HW / 4) + g];

        int id[4] = { m4.x ? l4.x : 0, m4.y ? l4.y : 0,
                      m4.z ? l4.z : 0, m4.w ? l4.w : 0 };
        int ix[4];
#pragma unroll
        for (int j = 0; j < 4; ++j) ix[j] = id[j] ? id[j] - 1 : 0;

        float ss[4] = { 0.f, 0.f, 0.f, 0.f };
#pragma unroll
        for (int c = 0; c < CCH; ++c) {
            float ev[4] = { e[c].x, e[c].y, e[c].z, e[c].w };
#pragma unroll
            for (int j = 0; j < 4; ++j) {
                float d = ev[j] - mt[c][ix[j]];
                ss[j] = fmaf(d, d, ss[j]);
            }
        }
#pragma unroll
        for (int j = 0; j < 4; ++j) {
            float d = sqrtf(fmaxf(ss[j], 1e-12f));
            float h = fmaxf(d - 0.5f, 0.f);
            float h2 = h * h;
#pragma unroll
            for (int s = 0; s < SEGS; ++s)
                pens[s] += (id[j] == s + 1) ? h2 : 0.f;   // id==0 binned nowhere
        }
    }

#pragma unroll
    for (int s = 0; s < SEGS; ++s) {
#pragma unroll
        for (int m = 32; m >= 1; m >>= 1) pens[s] += __shfl_xor(pens[s], m);
    }
    if (lane == 0) {
#pragma unroll
        for (int s = 0; s < SEGS; ++s) lpen[wave][s] = pens[s];   // exclusive writer
    }
    __syncthreads();
    if (threadIdx.x < SEGS) {
        float v = lpen[0][threadIdx.x] + lpen[1][threadIdx.x]
                + lpen[2][threadIdx.x] + lpen[3][threadIdx.x];
        if (v != 0.f) atomicAdd(&ws[1152 + b * SEGS + threadIdx.x], v);
    }
}

// ---------------------------------------------------------------------------
// Pass 3: finalize (unchanged, verified)
// ---------------------------------------------------------------------------
__global__ __launch_bounds__(256) void finalize_kernel(
    const float* __restrict__ ws, float* __restrict__ out)
{
    __shared__ float cnt[BATCH][SEGS];
    __shared__ float mu[BATCH][SEGS][CCH];
    __shared__ float pen[BATCH][SEGS];
    __shared__ float res[BATCH][3];

    for (int i = threadIdx.x; i < BATCH * SEGS; i += 256) {
        (&cnt[0][0])[i] = ws[i];
        (&pen[0][0])[i] = ws[1152 + i];
    }
    for (int i = threadIdx.x; i < BATCH * SEGS * CCH; i += 256) {
        float c = ws[i / CCH];
        (&mu[0][0][0])[i] = ws[128 + i] / fmaxf(c, 1.0f);
    }
    __syncthreads();

    const int b = threadIdx.x >> 5;   // 8 batches x 32-lane groups
    const int l = threadIdx.x & 31;

    float pullv = 0.f, Kf = 0.f;
    if (l < SEGS && cnt[b][l] > 0.f) {
        Kf = 1.f;
        pullv = pen[b][l] / cnt[b][l];       // count>0 => max(count,1)=count
    }
    float hs = 0.f, np = 0.f;
    for (int p = l; p < 256; p += 32) {
        int i = p >> 4, j = p & 15;
        if (i < j && cnt[b][i] > 0.f && cnt[b][j] > 0.f) {
            float ssq = 0.f;
#pragma unroll
            for (int c = 0; c < CCH; ++c) {
                float d = mu[b][i][c] - mu[b][j][c];
                ssq += d * d;
            }
            float dist = sqrtf(fmaxf(ssq, 1e-12f));
            float h = fmaxf(3.0f - dist, 0.f);   // 2*DELTA_D = 3.0
            hs += h * h;
            np += 1.f;
        }
    }
#pragma unroll
    for (int m = 16; m >= 1; m >>= 1) {
        pullv += __shfl_xor(pullv, m);
        Kf    += __shfl_xor(Kf, m);
        hs    += __shfl_xor(hs, m);
        np    += __shfl_xor(np, m);
    }
    if (l == 0) {
        res[b][0] = (Kf > 0.f) ? pullv / Kf : 0.f;
        res[b][1] = (np > 0.f) ? hs / np : 0.f;
        res[b][2] = (Kf > 0.f) ? 1.f : 0.f;
    }
    __syncthreads();
    if (threadIdx.x == 0) {
        float sp = 0.f, sh = 0.f, nv = 0.f;
        for (int bb = 0; bb < BATCH; ++bb) {
            sp += res[bb][0] * res[bb][2];
            sh += res[bb][1] * res[bb][2];
            nv += res[bb][2];
        }
        nv = fmaxf(nv, 1.f);
        out[0] = sp / nv;
        out[1] = sh / nv;
    }
}

extern "C" void kernel_launch(void* const* d_in, const int* in_sizes, int n_in,
                              void* d_out, int out_size, void* d_ws, size_t ws_size,
                              hipStream_t stream)
{
    const float* emb = (const float*)d_in[0];
    const int* lab = (const int*)d_in[1];
    const int* msk = (const int*)d_in[2];
    float* out = (float*)d_out;
    float* ws = (float*)d_ws;

    hipMemsetAsync(d_ws, 0, 1280 * sizeof(float), stream);
    dim3 grid(GX, BATCH);
    accum_kernel<<<grid, 256, 0, stream>>>(emb, lab, msk, ws);
    pull_kernel<<<grid, 256, 0, stream>>>(emb, lab, msk, ws);
    finalize_kernel<<<1, 256, 0, stream>>>(ws, out);
}

// Round 5
// 159.918 us; speedup vs baseline: 1.4295x; 1.4295x over previous
//
#include <hip/hip_runtime.h>

#define BATCH 8
#define CCH 8
#define HW 262144       // 512*512
#define SEGS 16         // segments 1..16 (segment 0 is provably ignored by the reference)
#define XB 64           // blocks per batch; grid (64,8) = 512 blocks = 2/CU
#define GPB (HW / 4 / XB)   // 1024 int4-groups per block
#define NITER (GPB / 256)   // 4 groups per thread

// ws float layout (NO atomics anywhere; every slot written before read):
//   P1    = 0     : [8][64][144] per-block partials: cnt[16], sums[s*8+c] (128)
//   MEANS = 73728 : [8][144]     batch-reduced cnt[16] + raw sums[128] (written by pull xb==0)
//   PP    = 74880 : [8][64][16]  per-block pull-penalty partials
//   total 83072 floats = 332 KB
#define P1 0
#define MEANS 73728
#define PP 74880

// ---------------------------------------------------------------------------
// Pass 1: counts + per-channel sums. R0-proven LDS-atomic accumulation
// (spill-proof, ~2 us chip-wide); commit = plain coalesced stores of the
// block-private partial. Zero global atomics.
// ---------------------------------------------------------------------------
__global__ __launch_bounds__(256) void accum_kernel(
    const float* __restrict__ emb, const int* __restrict__ lab,
    const int* __restrict__ msk, float* __restrict__ ws)
{
    const int b = blockIdx.y, xb = blockIdx.x;
    const int tid = threadIdx.x, wave = tid >> 6;
    __shared__ float lsum[4][SEGS][CCH];
    __shared__ float lcnt[4][SEGS];
    for (int i = tid; i < 4 * SEGS * CCH; i += 256) (&lsum[0][0][0])[i] = 0.f;
    for (int i = tid; i < 4 * SEGS; i += 256) (&lcnt[0][0])[i] = 0.f;
    __syncthreads();

    const int4* lb = (const int4*)(lab + (size_t)b * HW);
    const int4* mb = (const int4*)(msk + (size_t)b * HW);
    const float4* ep = (const float4*)(emb + (size_t)b * CCH * HW);
    const int base = xb * GPB;

#pragma unroll
    for (int q = 0; q < NITER; ++q) {
        const int g = base + q * 256 + tid;
        int4 l4 = lb[g];
        int4 m4 = mb[g];
        float4 e[CCH];
#pragma unroll
        for (int c = 0; c < CCH; ++c) e[c] = ep[(size_t)c * (HW / 4) + g];

        const int id0 = m4.x ? l4.x : 0;
        const int id1 = m4.y ? l4.y : 0;
        const int id2 = m4.z ? l4.z : 0;
        const int id3 = m4.w ? l4.w : 0;
        if (id0) atomicAdd(&lcnt[wave][id0 - 1], 1.f);
        if (id1) atomicAdd(&lcnt[wave][id1 - 1], 1.f);
        if (id2) atomicAdd(&lcnt[wave][id2 - 1], 1.f);
        if (id3) atomicAdd(&lcnt[wave][id3 - 1], 1.f);
#pragma unroll
        for (int c = 0; c < CCH; ++c) {
            if (id0) atomicAdd(&lsum[wave][id0 - 1][c], e[c].x);
            if (id1) atomicAdd(&lsum[wave][id1 - 1][c], e[c].y);
            if (id2) atomicAdd(&lsum[wave][id2 - 1][c], e[c].z);
            if (id3) atomicAdd(&lsum[wave][id3 - 1][c], e[c].w);
        }
    }
    __syncthreads();

    float* dst = ws + P1 + (b * XB + xb) * 144;
    if (tid < SEGS)
        dst[tid] = lcnt[0][tid] + lcnt[1][tid] + lcnt[2][tid] + lcnt[3][tid];
    if (tid < SEGS * CCH)
        dst[16 + tid] = (&lsum[0][0][0])[tid] + (&lsum[1][0][0])[tid]
                      + (&lsum[2][0][0])[tid] + (&lsum[3][0][0])[tid];
}

// ---------------------------------------------------------------------------
// Pass 2: each block reduces its batch's 64 partials from L2 (~36 KB) to
// build the mean table, then accumulates hinged pull penalties via LDS
// atomics; commit = plain store of the 16-float block partial. xb==0 blocks
// additionally persist the reduced cnt+sums for finalize.
// ---------------------------------------------------------------------------
__global__ __launch_bounds__(256) void pull_kernel(
    const float* __restrict__ emb, const int* __restrict__ lab,
    const int* __restrict__ msk, float* __restrict__ ws)
{
    const int b = blockIdx.y, xb = blockIdx.x;
    const int tid = threadIdx.x, wave = tid >> 6;
    __shared__ float sred[144];       // reduced cnt[16] + sums[128] for batch b
    __shared__ float mt[CCH][SEGS];   // transposed means
    __shared__ float lpen[4][SEGS];

    // batch-reduce the 64 partials (threads 0..143; independent loads, ILP)
    if (tid < 144) {
        const float* p = ws + P1 + (size_t)b * XB * 144 + tid;
        float acc = 0.f;
#pragma unroll 8
        for (int k = 0; k < XB; ++k) acc += p[k * 144];
        sred[tid] = acc;
        if (xb == 0) ws[MEANS + b * 144 + tid] = acc;   // persist for finalize
    }
    if (tid >= 144 && tid < 144 + 64) (&lpen[0][0])[tid - 144] = 0.f;
    __syncthreads();
    if (tid < SEGS * CCH) {
        int s = tid & (SEGS - 1);
        int c = tid >> 4;
        mt[c][s] = sred[16 + s * CCH + c] / fmaxf(sred[s], 1.0f);
    }
    __syncthreads();

    const int4* lb = (const int4*)(lab + (size_t)b * HW);
    const int4* mb = (const int4*)(msk + (size_t)b * HW);
    const float4* ep = (const float4*)(emb + (size_t)b * CCH * HW);
    const int base = xb * GPB;

#pragma unroll
    for (int q = 0; q < NITER; ++q) {
        const int g = base + q * 256 + tid;
        int4 l4 = lb[g];
        int4 m4 = mb[g];
        float4 e[CCH];
#pragma unroll
        for (int c = 0; c < CCH; ++c) e[c] = ep[(size_t)c * (HW / 4) + g];

        const int id0 = m4.x ? l4.x : 0;
        const int id1 = m4.y ? l4.y : 0;
        const int id2 = m4.z ? l4.z : 0;
        const int id3 = m4.w ? l4.w : 0;
        const int ix0 = id0 ? id0 - 1 : 0;
        const int ix1 = id1 ? id1 - 1 : 0;
        const int ix2 = id2 ? id2 - 1 : 0;
        const int ix3 = id3 ? id3 - 1 : 0;

        float ss0 = 0.f, ss1 = 0.f, ss2 = 0.f, ss3 = 0.f;
#pragma unroll
        for (int c = 0; c < CCH; ++c) {
            float d0 = e[c].x - mt[c][ix0];
            float d1 = e[c].y - mt[c][ix1];
            float d2 = e[c].z - mt[c][ix2];
            float d3 = e[c].w - mt[c][ix3];
            ss0 = fmaf(d0, d0, ss0);
            ss1 = fmaf(d1, d1, ss1);
            ss2 = fmaf(d2, d2, ss2);
            ss3 = fmaf(d3, d3, ss3);
        }
        if (id0) { float d = sqrtf(fmaxf(ss0, 1e-12f)); float h = fmaxf(d - 0.5f, 0.f); atomicAdd(&lpen[wave][ix0], h * h); }
        if (id1) { float d = sqrtf(fmaxf(ss1, 1e-12f)); float h = fmaxf(d - 0.5f, 0.f); atomicAdd(&lpen[wave][ix1], h * h); }
        if (id2) { float d = sqrtf(fmaxf(ss2, 1e-12f)); float h = fmaxf(d - 0.5f, 0.f); atomicAdd(&lpen[wave][ix2], h * h); }
        if (id3) { float d = sqrtf(fmaxf(ss3, 1e-12f)); float h = fmaxf(d - 0.5f, 0.f); atomicAdd(&lpen[wave][ix3], h * h); }
    }
    __syncthreads();
    if (tid < SEGS)
        ws[PP + (b * XB + xb) * 16 + tid] =
            lpen[0][tid] + lpen[1][tid] + lpen[2][tid] + lpen[3][tid];
}

// ---------------------------------------------------------------------------
// Pass 3: finalize. Reads MEANS (8x144) and reduces PP (8x64x16), then the
// verified epilogue (unchanged math).
// ---------------------------------------------------------------------------
__global__ __launch_bounds__(256) void finalize_kernel(
    const float* __restrict__ ws, float* __restrict__ out)
{
    __shared__ float cnt[BATCH][SEGS];
    __shared__ float mu[BATCH][SEGS][CCH];
    __shared__ float pen[BATCH][SEGS];
    __shared__ float res[BATCH][3];

    // load reduced cnt + raw sums
    for (int i = threadIdx.x; i < BATCH * 144; i += 256) {
        int bb = i / 144, t = i - bb * 144;
        float v = ws[MEANS + i];
        if (t < SEGS) cnt[bb][t] = v;
        else {
            int idx = t - 16;                  // s*8 + c
            mu[bb][idx >> 3][idx & 7] = v;     // raw sum for now
        }
    }
    // reduce pull-penalty partials
    if (threadIdx.x < BATCH * SEGS) {
        int bb = threadIdx.x >> 4, s = threadIdx.x & 15;
        const float* p = ws + PP + (size_t)bb * XB * 16 + s;
        float acc = 0.f;
#pragma unroll 8
        for (int k = 0; k < XB; ++k) acc += p[k * 16];
        pen[bb][s] = acc;
    }
    __syncthreads();
    // raw sums -> means
    for (int i = threadIdx.x; i < BATCH * SEGS * CCH; i += 256) {
        int bb = i >> 7, r = i & 127;
        mu[bb][r >> 3][r & 7] /= fmaxf(cnt[bb][r >> 3], 1.0f);
    }
    __syncthreads();

    const int b = threadIdx.x >> 5;   // 8 batches x 32-lane groups
    const int l = threadIdx.x & 31;

    float pullv = 0.f, Kf = 0.f;
    if (l < SEGS && cnt[b][l] > 0.f) {
        Kf = 1.f;
        pullv = pen[b][l] / cnt[b][l];       // count>0 => max(count,1)=count
    }
    float hs = 0.f, np = 0.f;
    for (int p = l; p < 256; p += 32) {
        int i = p >> 4, j = p & 15;
        if (i < j && cnt[b][i] > 0.f && cnt[b][j] > 0.f) {
            float ssq = 0.f;
#pragma unroll
            for (int c = 0; c < CCH; ++c) {
                float d = mu[b][i][c] - mu[b][j][c];
                ssq += d * d;
            }
            float dist = sqrtf(fmaxf(ssq, 1e-12f));
            float h = fmaxf(3.0f - dist, 0.f);   // 2*DELTA_D = 3.0
            hs += h * h;
            np += 1.f;
        }
    }
#pragma unroll
    for (int m = 16; m >= 1; m >>= 1) {
        pullv += __shfl_xor(pullv, m);
        Kf    += __shfl_xor(Kf, m);
        hs    += __shfl_xor(hs, m);
        np    += __shfl_xor(np, m);
    }
    if (l == 0) {
        res[b][0] = (Kf > 0.f) ? pullv / Kf : 0.f;
        res[b][1] = (np > 0.f) ? hs / np : 0.f;
        res[b][2] = (Kf > 0.f) ? 1.f : 0.f;
    }
    __syncthreads();
    if (threadIdx.x == 0) {
        float sp = 0.f, sh = 0.f, nv = 0.f;
        for (int bb = 0; bb < BATCH; ++bb) {
            sp += res[bb][0] * res[bb][2];
            sh += res[bb][1] * res[bb][2];
            nv += res[bb][2];
        }
        nv = fmaxf(nv, 1.f);
        out[0] = sp / nv;
        out[1] = sh / nv;
    }
}

extern "C" void kernel_launch(void* const* d_in, const int* in_sizes, int n_in,
                              void* d_out, int out_size, void* d_ws, size_t ws_size,
                              hipStream_t stream)
{
    const float* emb = (const float*)d_in[0];
    const int* lab = (const int*)d_in[1];
    const int* msk = (const int*)d_in[2];
    float* out = (float*)d_out;
    float* ws = (float*)d_ws;

    // no memset needed: every ws slot is written before it is read
    dim3 grid(XB, BATCH);
    accum_kernel<<<grid, 256, 0, stream>>>(emb, lab, msk, ws);
    pull_kernel<<<grid, 256, 0, stream>>>(emb, lab, msk, ws);
    finalize_kernel<<<1, 256, 0, stream>>>(ws, out);
}